// Round 7
// baseline (439.677 us; speedup 1.0000x reference)
//
#include <hip/hip_runtime.h>
#include <hip/hip_bf16.h>
#include <stdint.h>

#define NB 64
#define NT 1024
#define CIN 8
#define NE 256
#define NO 63
#define TPAD 16
#define TROWS (NT + 2*TPAD)   // 1056
#define LCH 128               // LIF chunk length
#define LWU 48                // LIF warm-up steps (2^-48 decay << fp32 ulp)

using f32x4  = __attribute__((ext_vector_type(4))) float;
using i32x4  = __attribute__((ext_vector_type(4))) int;

// ---- weight quantize: convs_w [3][E][E][3] fp32 -> two-level i8 frags + scales ----
// Wq [l][k][slot][e4(16)][cg(4)][lane(64)*16B]; w = sh*qh + (sh/256)*ql
__global__ void prep_w(const float* __restrict__ cw, signed char* __restrict__ wq,
                       float* __restrict__ sch, float* __restrict__ scl) {
    int l = blockIdx.x >> 8, e = blockIdx.x & 255;
    int lane = threadIdx.x;
    float w[4][3];
    float m = 0.0f;
    #pragma unroll
    for (int ci = 0; ci < 4; ++ci)
        #pragma unroll
        for (int k = 0; k < 3; ++k) {
            float v = cw[((size_t)((l*256 + e)*256) + lane*4 + ci)*3 + k];
            w[ci][k] = v; m = fmaxf(m, fabsf(v));
        }
    #pragma unroll
    for (int off = 1; off < 64; off <<= 1) m = fmaxf(m, __shfl_xor(m, off, 64));
    float sh = fmaxf(m, 1e-30f) * (1.0f/127.0f);
    float inv = 1.0f / sh;
    int e4 = e >> 4, n16 = e & 15;
    #pragma unroll
    for (int ci = 0; ci < 4; ++ci) {
        int c = lane*4 + ci;
        int cg = c >> 6, cr = c & 63;
        int fl = n16 + ((cr >> 4) << 4);
        int j = cr & 15;
        #pragma unroll
        for (int k = 0; k < 3; ++k) {
            float v = w[ci][k];
            float qh = rintf(v * inv);
            float resid = v - qh * sh;
            float ql = rintf(resid * inv * 256.0f);
            ql = fminf(fmaxf(ql, -127.0f), 127.0f);
            size_t base = ((((size_t)(l*3 + k)*2 + 0)*16 + e4)*4 + cg)*1024 + fl*16 + j;
            wq[base]         = (signed char)(int)qh;
            wq[base + 65536] = (signed char)(int)ql;   // slot stride = 16*4*1024
        }
    }
    if (lane == 0) { sch[l*256 + e] = sh; scl[l*256 + e] = sh * (1.0f/256.0f); }
}

// ---------------- conv0: x [B][T][CIN] -> y [B][T][E] fp32 (+bias) + block stats ----------
__global__ void conv0_kern(const float* __restrict__ x, const float* __restrict__ w0,
                           const float* __restrict__ b0, float* __restrict__ y,
                           float* __restrict__ part) {
    int b = blockIdx.y, tc = blockIdx.x;            // tc: 8 chunks of 128 t
    int e = threadIdx.x;
    int t0 = tc * 128;
    __shared__ float xs[1040];                      // 130 t-rows x 8 c
    for (int i = threadIdx.x; i < 1040; i += 256) {
        int t = t0 - 1 + (i >> 3); int c = i & 7;
        xs[i] = (t >= 0 && t < NT) ? x[((size_t)b*NT + t)*CIN + c] : 0.0f;
    }
    __syncthreads();
    float w[24];
    #pragma unroll
    for (int j = 0; j < 24; ++j) w[j] = w0[e*24 + j];   // [e][c][k]
    float bias = b0[e];
    float s = 0.0f, qq = 0.0f;
    for (int dt = 0; dt < 128; ++dt) {
        float acc = bias;
        #pragma unroll
        for (int c = 0; c < 8; ++c)
            #pragma unroll
            for (int k = 0; k < 3; ++k)
                acc += xs[(dt + k)*8 + c] * w[c*3 + k];
        y[((size_t)b*NT + t0 + dt)*NE + e] = acc;
        s += acc; qq += acc*acc;
    }
    int p = b*8 + tc;
    part[(size_t)p*512 + e]       = s;
    part[(size_t)p*512 + 256 + e] = qq;
}

// ---------------- stats final: reduce 512 partials per e, wave-parallel ----------------
__global__ void stats_final(const float* __restrict__ part, const float* __restrict__ gamma,
                            const float* __restrict__ beta, float4* __restrict__ lifp) {
    int e = blockIdx.x; int lane = threadIdx.x;
    double s = 0.0, q = 0.0;
    for (int p = lane; p < 512; p += 64) {
        s += (double)part[(size_t)p*512 + e];
        q += (double)part[(size_t)p*512 + 256 + e];
    }
    #pragma unroll
    for (int off = 1; off < 64; off <<= 1) {
        s += __shfl_xor(s, off, 64);
        q += __shfl_xor(q, off, 64);
    }
    if (lane == 0) {
        const double N = 65536.0;
        double mean = s / N;
        double var  = q / N - mean*mean;
        float rs = (float)(1.0 / sqrt(var + 1e-5));
        float4 o; o.x = (float)mean; o.y = rs * gamma[e]; o.z = beta[e]; o.w = 0.0f;
        lifp[e] = o;
    }
}

// ---------------- BN apply + chunked LIF scan; WS: write i8 spikes, else pool counts ----------
template<bool WS>
__global__ void lif_kern(const float* __restrict__ y, const float4* __restrict__ lifp,
                         signed char* __restrict__ S, float* __restrict__ pool) {
    int c = blockIdx.x, b = blockIdx.y;
    int e = threadIdx.x;
    float4 pr = lifp[e];
    float mu = pr.x, rsg = pr.y, bet = pr.z;
    if (WS) {
        if (c == 0) {       // zero top halo
            for (int r = 0; r < TPAD; ++r) S[((size_t)b*TROWS + r)*NE + e] = 0;
        }
        if (c == 7) {       // zero bottom halo
            for (int r = 0; r < TPAD; ++r) S[((size_t)b*TROWS + TPAD + NT + r)*NE + e] = 0;
        }
    }
    int t0 = c * LCH;
    int tw = t0 - LWU; if (tw < 0) tw = 0;
    const float* yb = y + (size_t)b*NT*NE + e;
    signed char* sb = S + ((size_t)b*TROWS + TPAD)*NE + e;
    float v = 0.0f;
    #pragma unroll 4
    for (int t = tw; t < t0; ++t) {                 // warm-up, no writes
        float xx = yb[(size_t)t*NE];
        float yn = (xx - mu)*rsg + bet;
        float d  = __fsub_rn(yn, v);
        v = __fadd_rn(v, __fmul_rn(d, 0.5f));
        v = (v >= 1.0f) ? 0.0f : v;
    }
    float cnt = 0.0f;
    #pragma unroll 4
    for (int t = t0; t < t0 + LCH; ++t) {
        float xx = yb[(size_t)t*NE];
        float yn = (xx - mu)*rsg + bet;
        float d  = __fsub_rn(yn, v);
        v = __fadd_rn(v, __fmul_rn(d, 0.5f));       // v + (x - v)/TAU, TAU=2
        bool sp = (v >= 1.0f);
        if (WS) sb[(size_t)t*NE] = sp ? 1 : 0;
        else    cnt += sp ? 1.0f : 0.0f;
        v = sp ? 0.0f : v;
    }
    if (!WS) pool[(size_t)(b*8 + c)*256 + e] = cnt;
}

// ---- main conv v6: i8 two-level MFMA, full-K LDS stage (2 barriers), A direct from L2 ----
// block: 128e x 128t, 4 waves (we,wt); wave: 64e x 64t (f=4 e-blocks x g=4 t-blocks of 16x16x64)
__global__ __launch_bounds__(256, 2) void conv_mfma(
    const signed char* __restrict__ Sp,   // [B][TROWS][E] padded i8 spikes
    const signed char* __restrict__ Wq,   // [k][slot][e4][cg][1024] frag-ordered, this layer
    const float* __restrict__ sch, const float* __restrict__ scl,
    const float* __restrict__ bias,
    float* __restrict__ y,                // [B][T][E]
    float* __restrict__ part)
{
    __shared__ signed char Bbuf[130*272]; // 130 t-rows x 256 c + 16 pad = 35360 B
    const int tid  = threadIdx.x;
    const int wave = tid >> 6, lane = tid & 63;
    const int n16  = lane & 15, q = lane >> 4;
    const int we = wave & 1, wt = wave >> 1;
    const int tt = blockIdx.x, et = blockIdx.y, b = blockIdx.z;
    const int t0 = tt * 128;

    const signed char* Sbase = Sp + ((size_t)b*TROWS + (TPAD - 1 + t0)) * NE;
    // stage full K: 130 rows x 256 B
    for (int idx = tid; idx < 130*16; idx += 256) {
        int r = idx >> 4, sg = idx & 15;
        uint4 d = *(const uint4*)(Sbase + (size_t)r*NE + sg*16);
        *(uint4*)(Bbuf + r*272 + sg*16) = d;
    }
    __syncthreads();

    // ---- pass hi ----
    i32x4 acch[4][4] = {};
    #pragma unroll
    for (int cg = 0; cg < 4; ++cg)
        #pragma unroll
        for (int kk = 0; kk < 3; ++kk) {
            i32x4 bfr[4];
            #pragma unroll
            for (int g = 0; g < 4; ++g) {
                int row = wt*64 + g*16 + n16 + kk;
                bfr[g] = *(const i32x4*)(Bbuf + row*272 + cg*64 + q*16);
            }
            i32x4 afr[4];
            #pragma unroll
            for (int f = 0; f < 4; ++f)
                afr[f] = *(const i32x4*)(Wq + ((((size_t)(kk*2 + 0)*16 + (et*8 + we*4 + f))*4 + cg) << 10) + lane*16);
            #pragma unroll
            for (int f = 0; f < 4; ++f)
                #pragma unroll
                for (int g = 0; g < 4; ++g)
                    acch[f][g] = __builtin_amdgcn_mfma_i32_16x16x64_i8(afr[f], bfr[g], acch[f][g], 0, 0, 0);
        }
    // convert with per-e hi scale
    f32x4 accf[4][4];
    #pragma unroll
    for (int f = 0; f < 4; ++f) {
        float4 s4 = *(const float4*)(sch + et*128 + we*64 + f*16 + q*4);
        #pragma unroll
        for (int g = 0; g < 4; ++g) {
            accf[f][g][0] = (float)acch[f][g][0] * s4.x;
            accf[f][g][1] = (float)acch[f][g][1] * s4.y;
            accf[f][g][2] = (float)acch[f][g][2] * s4.z;
            accf[f][g][3] = (float)acch[f][g][3] * s4.w;
        }
    }
    // ---- pass lo ----
    i32x4 accl[4][4] = {};
    #pragma unroll
    for (int cg = 0; cg < 4; ++cg)
        #pragma unroll
        for (int kk = 0; kk < 3; ++kk) {
            i32x4 bfr[4];
            #pragma unroll
            for (int g = 0; g < 4; ++g) {
                int row = wt*64 + g*16 + n16 + kk;
                bfr[g] = *(const i32x4*)(Bbuf + row*272 + cg*64 + q*16);
            }
            i32x4 afr[4];
            #pragma unroll
            for (int f = 0; f < 4; ++f)
                afr[f] = *(const i32x4*)(Wq + ((((size_t)(kk*2 + 1)*16 + (et*8 + we*4 + f))*4 + cg) << 10) + lane*16);
            #pragma unroll
            for (int f = 0; f < 4; ++f)
                #pragma unroll
                for (int g = 0; g < 4; ++g)
                    accl[f][g] = __builtin_amdgcn_mfma_i32_16x16x64_i8(afr[f], bfr[g], accl[f][g], 0, 0, 0);
        }

    // epilogue: C col=n16 (t), row=q*4+reg (e); o = accf + sl*accl + bias; store + stats
    float ls[16], lq[16];
    #pragma unroll
    for (int f = 0; f < 4; ++f) {
        int e_loc = et*128 + we*64 + f*16 + q*4;
        float4 bv = *(const float4*)(bias + e_loc);
        float4 l4 = *(const float4*)(scl + e_loc);
        float s0=0,s1=0,s2=0,s3=0, q0=0,q1=0,q2=0,q3=0;
        #pragma unroll
        for (int g = 0; g < 4; ++g) {
            int t = t0 + wt*64 + g*16 + n16;
            float4 o;
            o.x = accf[f][g][0] + l4.x*(float)accl[f][g][0] + bv.x;
            o.y = accf[f][g][1] + l4.y*(float)accl[f][g][1] + bv.y;
            o.z = accf[f][g][2] + l4.z*(float)accl[f][g][2] + bv.z;
            o.w = accf[f][g][3] + l4.w*(float)accl[f][g][3] + bv.w;
            *(float4*)(y + ((size_t)b*NT + t)*NE + e_loc) = o;
            s0 += o.x; q0 += o.x*o.x;
            s1 += o.y; q1 += o.y*o.y;
            s2 += o.z; q2 += o.z*o.z;
            s3 += o.w; q3 += o.w*o.w;
        }
        ls[f*4+0]=s0; lq[f*4+0]=q0;
        ls[f*4+1]=s1; lq[f*4+1]=q1;
        ls[f*4+2]=s2; lq[f*4+2]=q2;
        ls[f*4+3]=s3; lq[f*4+3]=q3;
    }
    #pragma unroll
    for (int off = 1; off < 16; off <<= 1) {
        #pragma unroll
        for (int i = 0; i < 16; ++i) {
            ls[i] += __shfl_xor(ls[i], off, 64);
            lq[i] += __shfl_xor(lq[i], off, 64);
        }
    }
    __syncthreads();
    float* red = (float*)Bbuf;                  // reuse LDS: [0..127]=sum, [128..255]=sq
    if (n16 == 0 && wt == 0) {
        #pragma unroll
        for (int f = 0; f < 4; ++f)
            #pragma unroll
            for (int r = 0; r < 4; ++r) {
                int el = we*64 + f*16 + q*4 + r;
                red[el] = ls[f*4+r]; red[128+el] = lq[f*4+r];
            }
    }
    __syncthreads();
    if (n16 == 0 && wt == 1) {
        #pragma unroll
        for (int f = 0; f < 4; ++f)
            #pragma unroll
            for (int r = 0; r < 4; ++r) {
                int el = we*64 + f*16 + q*4 + r;
                red[el] += ls[f*4+r]; red[128+el] += lq[f*4+r];
            }
    }
    __syncthreads();
    if (tid < 128) {
        int p = b*8 + tt;
        part[(size_t)p*512 + et*128 + tid]       = red[tid];
        part[(size_t)p*512 + 256 + et*128 + tid] = red[128 + tid];
    }
}

// ---------------- head final: pooled counts -> [B,E]@[O,E]^T + b ----------------
__global__ void head_final(const float* __restrict__ pool, const float* __restrict__ hw,
                           const float* __restrict__ hb, float* __restrict__ out) {
    int b = blockIdx.x;
    int tid = threadIdx.x;
    __shared__ float pooled[256];
    float s = 0.0f;
    #pragma unroll
    for (int c = 0; c < 8; ++c) s += pool[(size_t)(b*8 + c)*256 + tid];
    pooled[tid] = s * (1.0f/1024.0f);        // exact: integer count / 2^10
    __syncthreads();
    if (tid < NO) {
        float acc = hb[tid];
        for (int c = 0; c < 256; ++c) acc += pooled[c] * hw[tid*256 + c];
        out[b*NO + tid] = acc;
    }
}

// ---------------- launch ----------------
extern "C" void kernel_launch(void* const* d_in, const int* in_sizes, int n_in,
                              void* d_out, int out_size, void* d_ws, size_t ws_size,
                              hipStream_t stream) {
    (void)in_sizes; (void)n_in; (void)out_size; (void)ws_size;
    const float* x       = (const float*)d_in[0];
    const float* conv0_w = (const float*)d_in[1];
    const float* conv0_b = (const float*)d_in[2];
    const float* convs_w = (const float*)d_in[3];
    const float* convs_b = (const float*)d_in[4];
    const float* bn_g    = (const float*)d_in[5];
    const float* bn_b    = (const float*)d_in[6];
    const float* head_w  = (const float*)d_in[7];
    const float* head_b  = (const float*)d_in[8];
    float* out = (float*)d_out;

    char* ws = (char*)d_ws;
    float*       y    = (float*)ws;                          // 67108864 B
    signed char* S    = (signed char*)(ws + 67108864);       // 17301504 B
    signed char* Wq   = (signed char*)(ws + 84410368);       //  1179648 B
    float*       sch  = (float*)(ws + 85590016);             //     3072 B
    float*       scl  = (float*)(ws + 85593088);             //     3072 B
    float*       part = (float*)(ws + 85598208);             //  1048576 B (512p x 512)
    float*       pool = (float*)(ws + 86646784);             //   524288 B
    float4*      lifp = (float4*)(ws + 87171072);            //     4096 B

    prep_w<<<768, 64, 0, stream>>>(convs_w, Wq, sch, scl);
    conv0_kern<<<dim3(8, 64), 256, 0, stream>>>(x, conv0_w, conv0_b, y, part);
    stats_final<<<256, 64, 0, stream>>>(part, bn_g, bn_b, lifp);
    lif_kern<true><<<dim3(8, 64), 256, 0, stream>>>(y, lifp, S, nullptr);

    for (int l = 0; l < 3; ++l) {
        conv_mfma<<<dim3(8, 2, 64), 256, 0, stream>>>(S, Wq + (size_t)l*393216,
                                                      sch + l*256, scl + l*256,
                                                      convs_b + l*256, y, part);
        stats_final<<<256, 64, 0, stream>>>(part, bn_g + (l+1)*256, bn_b + (l+1)*256, lifp);
        if (l < 2) lif_kern<true ><<<dim3(8, 64), 256, 0, stream>>>(y, lifp, S, nullptr);
        else       lif_kern<false><<<dim3(8, 64), 256, 0, stream>>>(y, lifp, S, pool);
    }
    head_final<<<64, 256, 0, stream>>>(pool, head_w, head_b, out);
}

// Round 8
// 411.827 us; speedup vs baseline: 1.0676x; 1.0676x over previous
//
#include <hip/hip_runtime.h>
#include <hip/hip_bf16.h>
#include <stdint.h>

#define NB 64
#define NT 1024
#define CIN 8
#define NE 256
#define NO 63
#define TPAD 16
#define TROWS (NT + 2*TPAD)   // 1056
#define LCH 128               // LIF chunk length
#define LWU 48                // LIF warm-up steps (2^-48 decay << fp32 ulp)

using bf16x8 = __attribute__((ext_vector_type(8))) short;
using f32x4  = __attribute__((ext_vector_type(4))) float;

// ---- weight split + fragment reorder: convs_w [3][E][E][3] fp32 ->
//      Wfr [l][k][s][e4(16)][cph(8)][lane(64)*8]  bf16, per-lane A-frag order ----
__global__ void prep_w(const float* __restrict__ cw, __hip_bfloat16* __restrict__ wfr) {
    int F = blockIdx.x * 256 + threadIdx.x;          // 576 blocks -> 147456 lanes
    int lane = F & 63;
    int x = F >> 6;
    int cph = x & 7;  x >>= 3;
    int e4  = x & 15; x >>= 4;
    int s   = x & 1;  x >>= 1;
    int k   = x % 3;
    int l   = x / 3;
    int e = e4*16 + (lane & 15);
    int cb = cph*32 + (lane >> 4)*8;
    __hip_bfloat16 outv[8];
    #pragma unroll
    for (int j = 0; j < 8; ++j) {
        float w = cw[((size_t)(l*256 + e)*256 + (cb + j))*3 + k];
        __hip_bfloat16 hi = __float2bfloat16(w);
        if (s == 0) outv[j] = hi;
        else        outv[j] = __float2bfloat16(w - __bfloat162float(hi));
    }
    *(uint4*)(wfr + (size_t)F*8) = *(uint4*)outv;
}

// ---------------- conv0: x [B][T][CIN] -> y [B][T][E] fp32 (+bias) + block stats ----------
__global__ void conv0_kern(const float* __restrict__ x, const float* __restrict__ w0,
                           const float* __restrict__ b0, float* __restrict__ y,
                           float* __restrict__ part) {
    int b = blockIdx.y, tc = blockIdx.x;            // tc: 8 chunks of 128 t
    int e = threadIdx.x;
    int t0 = tc * 128;
    __shared__ float xs[1040];                      // 130 t-rows x 8 c
    for (int i = threadIdx.x; i < 1040; i += 256) {
        int t = t0 - 1 + (i >> 3); int c = i & 7;
        xs[i] = (t >= 0 && t < NT) ? x[((size_t)b*NT + t)*CIN + c] : 0.0f;
    }
    __syncthreads();
    float w[24];
    #pragma unroll
    for (int j = 0; j < 24; ++j) w[j] = w0[e*24 + j];   // [e][c][k]
    float bias = b0[e];
    float s = 0.0f, qq = 0.0f;
    for (int dt = 0; dt < 128; ++dt) {
        float acc = bias;
        #pragma unroll
        for (int c = 0; c < 8; ++c)
            #pragma unroll
            for (int k = 0; k < 3; ++k)
                acc += xs[(dt + k)*8 + c] * w[c*3 + k];
        y[((size_t)b*NT + t0 + dt)*NE + e] = acc;
        s += acc; qq += acc*acc;
    }
    int p = b*8 + tc;
    part[(size_t)p*512 + e]       = s;
    part[(size_t)p*512 + 256 + e] = qq;
}

// ---------------- stats final: reduce 512 partials per e, wave-parallel ----------------
__global__ void stats_final(const float* __restrict__ part, const float* __restrict__ gamma,
                            const float* __restrict__ beta, float4* __restrict__ lifp) {
    int e = blockIdx.x; int lane = threadIdx.x;
    double s = 0.0, q = 0.0;
    for (int p = lane; p < 512; p += 64) {
        s += (double)part[(size_t)p*512 + e];
        q += (double)part[(size_t)p*512 + 256 + e];
    }
    #pragma unroll
    for (int off = 1; off < 64; off <<= 1) {
        s += __shfl_xor(s, off, 64);
        q += __shfl_xor(q, off, 64);
    }
    if (lane == 0) {
        const double N = 65536.0;
        double mean = s / N;
        double var  = q / N - mean*mean;
        float rs = (float)(1.0 / sqrt(var + 1e-5));
        float4 o; o.x = (float)mean; o.y = rs * gamma[e]; o.z = beta[e]; o.w = 0.0f;
        lifp[e] = o;
    }
}

// ---------------- BN apply + chunked LIF scan; WS: write spikes, else pool counts ----------
template<bool WS>
__global__ void lif_kern(const float* __restrict__ y, const float4* __restrict__ lifp,
                         __hip_bfloat16* __restrict__ S, float* __restrict__ pool) {
    int c = blockIdx.x, b = blockIdx.y;
    int e = threadIdx.x;
    float4 pr = lifp[e];
    float mu = pr.x, rsg = pr.y, bet = pr.z;
    const __hip_bfloat16 z   = __float2bfloat16(0.0f);
    const __hip_bfloat16 one = __float2bfloat16(1.0f);
    if (WS) {
        if (c == 0) {       // zero top halo
            for (int r = 0; r < TPAD; ++r) S[((size_t)b*TROWS + r)*NE + e] = z;
        }
        if (c == 7) {       // zero bottom halo
            for (int r = 0; r < TPAD; ++r) S[((size_t)b*TROWS + TPAD + NT + r)*NE + e] = z;
        }
    }
    int t0 = c * LCH;
    int tw = t0 - LWU; if (tw < 0) tw = 0;
    const float* yb = y + (size_t)b*NT*NE + e;
    __hip_bfloat16* sb = S + ((size_t)b*TROWS + TPAD)*NE + e;
    float v = 0.0f;
    #pragma unroll 4
    for (int t = tw; t < t0; ++t) {                 // warm-up, no writes
        float xx = yb[(size_t)t*NE];
        float yn = (xx - mu)*rsg + bet;
        float d  = __fsub_rn(yn, v);
        v = __fadd_rn(v, __fmul_rn(d, 0.5f));
        v = (v >= 1.0f) ? 0.0f : v;
    }
    float cnt = 0.0f;
    #pragma unroll 4
    for (int t = t0; t < t0 + LCH; ++t) {
        float xx = yb[(size_t)t*NE];
        float yn = (xx - mu)*rsg + bet;
        float d  = __fsub_rn(yn, v);
        v = __fadd_rn(v, __fmul_rn(d, 0.5f));       // v + (x - v)/TAU, TAU=2
        bool sp = (v >= 1.0f);
        if (WS) sb[(size_t)t*NE] = sp ? one : z;
        else    cnt += sp ? 1.0f : 0.0f;
        v = sp ? 0.0f : v;
    }
    if (!WS) pool[(size_t)(b*8 + c)*256 + e] = cnt;
}

// ---- main conv v7: bf16 hi/lo, small tiles for 4 blocks/CU (whole grid co-resident) ----
// grid (8tt, 2et, 64b) = 1024 blocks; block 128e x 128t, 4 waves (we,wt); wave 64e x 64t
#define SROWS 130               // staged B rows per phase (128 t + 2 halo)

__global__ __launch_bounds__(256, 4) void conv_mfma(
    const __hip_bfloat16* __restrict__ Sp,   // [B][TROWS][E] padded spikes
    const __hip_bfloat16* __restrict__ Wfr,  // [k][s][e4][cph][512] frag-ordered, this layer
    const float* __restrict__ bias,
    float* __restrict__ y,                   // [B][T][E]
    float* __restrict__ part)
{
    __shared__ short Bbuf[SROWS*64];         // 130 rows x 64 c (128 B/row, seg-swizzled) = 16640 B
    const int tid  = threadIdx.x;
    const int wave = tid >> 6, lane = tid & 63;
    const int n16  = lane & 15, q = lane >> 4;
    const int we = wave & 1, wt = wave >> 1;
    const int tt = blockIdx.x, et = blockIdx.y, b = blockIdx.z;
    const int t0 = tt * 128;

    f32x4 acc[4][4] = {};
    bf16x8 bfr[4];

    const __hip_bfloat16* Sbase = Sp + ((size_t)b*TROWS + (TPAD - 1 + t0)) * NE;

    for (int ph = 0; ph < 4; ++ph) {
        const int c0 = ph * 64;
        __syncthreads();
        // stage B tile: 130 rows x 64 c; 16B segs swizzled by (row & 7)
        for (int idx = tid; idx < SROWS*8; idx += 256) {
            int r = idx >> 3, sg = idx & 7;
            uint4 d = *(const uint4*)(Sbase + (size_t)r*NE + c0 + sg*8);
            int sgs = sg ^ (r & 7);
            *(uint4*)((char*)Bbuf + r*128 + sgs*16) = d;
        }
        __syncthreads();
        #pragma unroll 1
        for (int kk = 0; kk < 3; ++kk) {
            #pragma unroll
            for (int cc = 0; cc < 2; ++cc) {
                #pragma unroll
                for (int g = 0; g < 4; ++g) {
                    int row = wt*64 + g*16 + n16 + kk;
                    int sgs = (cc*4 + q) ^ (row & 7);
                    bfr[g] = *(const bf16x8*)((const char*)Bbuf + row*128 + sgs*16);
                }
                #pragma unroll
                for (int s = 0; s < 2; ++s) {
                    const __hip_bfloat16* wb = Wfr
                        + ((((size_t)(kk*2 + s)*16 + (et*8 + we*4))*8 + (ph*2 + cc)) << 9) + lane*8;
                    #pragma unroll
                    for (int f = 0; f < 4; ++f) {
                        bf16x8 afr = *(const bf16x8*)(wb + ((size_t)f << 12));
                        #pragma unroll
                        for (int g = 0; g < 4; ++g)
                            acc[f][g] = __builtin_amdgcn_mfma_f32_16x16x32_bf16(afr, bfr[g], acc[f][g], 0, 0, 0);
                    }
                }
            }
        }
    }

    // epilogue: C col=n16 (t), row=q*4+reg (e); store y + per-e block stats
    float ls[16], lq[16];
    #pragma unroll
    for (int f = 0; f < 4; ++f) {
        int e_loc = et*128 + we*64 + f*16 + q*4;
        float4 bv = *(const float4*)(bias + e_loc);
        float s0=0,s1=0,s2=0,s3=0, q0=0,q1=0,q2=0,q3=0;
        #pragma unroll
        for (int g = 0; g < 4; ++g) {
            int t = t0 + wt*64 + g*16 + n16;
            f32x4 a = acc[f][g];
            float4 o;
            o.x = a[0] + bv.x; o.y = a[1] + bv.y; o.z = a[2] + bv.z; o.w = a[3] + bv.w;
            *(float4*)(y + ((size_t)b*NT + t)*NE + e_loc) = o;
            s0 += o.x; q0 += o.x*o.x;
            s1 += o.y; q1 += o.y*o.y;
            s2 += o.z; q2 += o.z*o.z;
            s3 += o.w; q3 += o.w*o.w;
        }
        ls[f*4+0]=s0; lq[f*4+0]=q0;
        ls[f*4+1]=s1; lq[f*4+1]=q1;
        ls[f*4+2]=s2; lq[f*4+2]=q2;
        ls[f*4+3]=s3; lq[f*4+3]=q3;
    }
    #pragma unroll
    for (int off = 1; off < 16; off <<= 1) {
        #pragma unroll
        for (int i = 0; i < 16; ++i) {
            ls[i] += __shfl_xor(ls[i], off, 64);
            lq[i] += __shfl_xor(lq[i], off, 64);
        }
    }
    __syncthreads();
    float* red = (float*)Bbuf;                  // reuse LDS: [0..127]=sum, [128..255]=sq
    if (n16 == 0 && wt == 0) {
        #pragma unroll
        for (int f = 0; f < 4; ++f)
            #pragma unroll
            for (int r = 0; r < 4; ++r) {
                int el = we*64 + f*16 + q*4 + r;
                red[el] = ls[f*4+r]; red[128+el] = lq[f*4+r];
            }
    }
    __syncthreads();
    if (n16 == 0 && wt == 1) {
        #pragma unroll
        for (int f = 0; f < 4; ++f)
            #pragma unroll
            for (int r = 0; r < 4; ++r) {
                int el = we*64 + f*16 + q*4 + r;
                red[el] += ls[f*4+r]; red[128+el] += lq[f*4+r];
            }
    }
    __syncthreads();
    if (tid < 128) {
        int p = b*8 + tt;
        part[(size_t)p*512 + et*128 + tid]       = red[tid];
        part[(size_t)p*512 + 256 + et*128 + tid] = red[128 + tid];
    }
}

// ---------------- head final: pooled counts -> [B,E]@[O,E]^T + b ----------------
__global__ void head_final(const float* __restrict__ pool, const float* __restrict__ hw,
                           const float* __restrict__ hb, float* __restrict__ out) {
    int b = blockIdx.x;
    int tid = threadIdx.x;
    __shared__ float pooled[256];
    float s = 0.0f;
    #pragma unroll
    for (int c = 0; c < 8; ++c) s += pool[(size_t)(b*8 + c)*256 + tid];
    pooled[tid] = s * (1.0f/1024.0f);        // exact: integer count / 2^10
    __syncthreads();
    if (tid < NO) {
        float acc = hb[tid];
        for (int c = 0; c < 256; ++c) acc += pooled[c] * hw[tid*256 + c];
        out[b*NO + tid] = acc;
    }
}

// ---------------- launch ----------------
extern "C" void kernel_launch(void* const* d_in, const int* in_sizes, int n_in,
                              void* d_out, int out_size, void* d_ws, size_t ws_size,
                              hipStream_t stream) {
    (void)in_sizes; (void)n_in; (void)out_size; (void)ws_size;
    const float* x       = (const float*)d_in[0];
    const float* conv0_w = (const float*)d_in[1];
    const float* conv0_b = (const float*)d_in[2];
    const float* convs_w = (const float*)d_in[3];
    const float* convs_b = (const float*)d_in[4];
    const float* bn_g    = (const float*)d_in[5];
    const float* bn_b    = (const float*)d_in[6];
    const float* head_w  = (const float*)d_in[7];
    const float* head_b  = (const float*)d_in[8];
    float* out = (float*)d_out;

    char* ws = (char*)d_ws;
    float*          y      = (float*)ws;                              // 67108864 B
    __hip_bfloat16* S      = (__hip_bfloat16*)(ws + 67108864);        // 34603008 B
    __hip_bfloat16* Wfr    = (__hip_bfloat16*)(ws + 101711872);       //  2359296 B
    float*          part   = (float*)(ws + 104071168);                //  1048576 B (512p x 512)
    float4*         lifp   = (float4*)(ws + 105119744);               //     4096 B
    float*          pool   = (float*)(ws + 105123840);                //   524288 B

    prep_w<<<576, 256, 0, stream>>>(convs_w, Wfr);
    conv0_kern<<<dim3(8, 64), 256, 0, stream>>>(x, conv0_w, conv0_b, y, part);
    stats_final<<<256, 64, 0, stream>>>(part, bn_g, bn_b, lifp);
    lif_kern<true><<<dim3(8, 64), 256, 0, stream>>>(y, lifp, S, nullptr);

    for (int l = 0; l < 3; ++l) {
        conv_mfma<<<dim3(8, 2, 64), 256, 0, stream>>>(S, Wfr + (size_t)l*393216,
                                                      convs_b + l*256, y, part);
        stats_final<<<256, 64, 0, stream>>>(part, bn_g + (l+1)*256, bn_b + (l+1)*256, lifp);
        if (l < 2) lif_kern<true ><<<dim3(8, 64), 256, 0, stream>>>(y, lifp, S, nullptr);
        else       lif_kern<false><<<dim3(8, 64), 256, 0, stream>>>(y, lifp, S, pool);
    }
    head_final<<<64, 256, 0, stream>>>(pool, head_w, head_b, out);
}

// Round 9
// 376.845 us; speedup vs baseline: 1.1667x; 1.0928x over previous
//
#include <hip/hip_runtime.h>
#include <hip/hip_bf16.h>
#include <stdint.h>

#define NB 64
#define NT 1024
#define CIN 8
#define NE 256
#define NO 63
#define TPAD 16
#define TROWS (NT + 2*TPAD)   // 1056
#define LCH 128               // LIF chunk length
#define LWU 48                // LIF warm-up steps (2^-48 decay << fp32 ulp)
#define TT 256                // conv t-tile per block

using bf16x8 = __attribute__((ext_vector_type(8))) short;
using f32x4  = __attribute__((ext_vector_type(4))) float;

// ---- combined: blocks 0..511 = conv0 (x -> y + stats), blocks 512..1087 = weight prep ----
// Wfr [l][k][s][e4(16)][cph(8)][lane(64)*8]  bf16, per-lane A-frag order
__global__ void conv0_prep(const float* __restrict__ x, const float* __restrict__ w0,
                           const float* __restrict__ b0, float* __restrict__ y,
                           float* __restrict__ part,
                           const float* __restrict__ cw, __hip_bfloat16* __restrict__ wfr) {
    int bid = blockIdx.x;
    if (bid >= 512) {                               // ---- prep_w path ----
        int F = (bid - 512) * 256 + threadIdx.x;    // 576 blocks -> 147456 lanes
        int lane = F & 63;
        int xx = F >> 6;
        int cph = xx & 7;  xx >>= 3;
        int e4  = xx & 15; xx >>= 4;
        int s   = xx & 1;  xx >>= 1;
        int k   = xx % 3;
        int l   = xx / 3;
        int e = e4*16 + (lane & 15);
        int cb = cph*32 + (lane >> 4)*8;
        __hip_bfloat16 outv[8];
        #pragma unroll
        for (int j = 0; j < 8; ++j) {
            float w = cw[((size_t)(l*256 + e)*256 + (cb + j))*3 + k];
            __hip_bfloat16 hi = __float2bfloat16(w);
            if (s == 0) outv[j] = hi;
            else        outv[j] = __float2bfloat16(w - __bfloat162float(hi));
        }
        *(uint4*)(wfr + (size_t)F*8) = *(uint4*)outv;
        return;
    }
    // ---- conv0 path ----
    int b = bid >> 3, tc = bid & 7;                 // tc: 8 chunks of 128 t
    int e = threadIdx.x;
    int t0 = tc * 128;
    __shared__ float xs[1040];                      // 130 t-rows x 8 c
    for (int i = threadIdx.x; i < 1040; i += 256) {
        int t = t0 - 1 + (i >> 3); int c = i & 7;
        xs[i] = (t >= 0 && t < NT) ? x[((size_t)b*NT + t)*CIN + c] : 0.0f;
    }
    __syncthreads();
    float w[24];
    #pragma unroll
    for (int j = 0; j < 24; ++j) w[j] = w0[e*24 + j];   // [e][c][k]
    float bias = b0[e];
    float s = 0.0f, qq = 0.0f;
    for (int dt = 0; dt < 128; ++dt) {
        float acc = bias;
        #pragma unroll
        for (int c = 0; c < 8; ++c)
            #pragma unroll
            for (int k = 0; k < 3; ++k)
                acc += xs[(dt + k)*8 + c] * w[c*3 + k];
        y[((size_t)b*NT + t0 + dt)*NE + e] = acc;
        s += acc; qq += acc*acc;
    }
    int p = b*8 + tc;
    part[(size_t)p*512 + e]       = s;
    part[(size_t)p*512 + 256 + e] = qq;
}

// ---------------- stats final: reduce np partials per e, wave-parallel ----------------
__global__ void stats_final(const float* __restrict__ part, const float* __restrict__ gamma,
                            const float* __restrict__ beta, float4* __restrict__ lifp, int np) {
    int e = blockIdx.x; int lane = threadIdx.x;
    double s = 0.0, q = 0.0;
    for (int p = lane; p < np; p += 64) {
        s += (double)part[(size_t)p*512 + e];
        q += (double)part[(size_t)p*512 + 256 + e];
    }
    #pragma unroll
    for (int off = 1; off < 64; off <<= 1) {
        s += __shfl_xor(s, off, 64);
        q += __shfl_xor(q, off, 64);
    }
    if (lane == 0) {
        const double N = 65536.0;
        double mean = s / N;
        double var  = q / N - mean*mean;
        float rs = (float)(1.0 / sqrt(var + 1e-5));
        float4 o; o.x = (float)mean; o.y = rs * gamma[e]; o.z = beta[e]; o.w = 0.0f;
        lifp[e] = o;
    }
}

// ---------------- BN apply + chunked LIF scan; WS: write spikes, else pool counts ----------
template<bool WS>
__global__ void lif_kern(const float* __restrict__ y, const float4* __restrict__ lifp,
                         __hip_bfloat16* __restrict__ S, float* __restrict__ pool) {
    int c = blockIdx.x, b = blockIdx.y;
    int e = threadIdx.x;
    float4 pr = lifp[e];
    float mu = pr.x, rsg = pr.y, bet = pr.z;
    const __hip_bfloat16 z   = __float2bfloat16(0.0f);
    const __hip_bfloat16 one = __float2bfloat16(1.0f);
    if (WS) {
        if (c == 0) {       // zero top halo
            for (int r = 0; r < TPAD; ++r) S[((size_t)b*TROWS + r)*NE + e] = z;
        }
        if (c == 7) {       // zero bottom halo
            for (int r = 0; r < TPAD; ++r) S[((size_t)b*TROWS + TPAD + NT + r)*NE + e] = z;
        }
    }
    int t0 = c * LCH;
    int tw = t0 - LWU; if (tw < 0) tw = 0;
    const float* yb = y + (size_t)b*NT*NE + e;
    __hip_bfloat16* sb = S + ((size_t)b*TROWS + TPAD)*NE + e;
    float v = 0.0f;
    #pragma unroll 4
    for (int t = tw; t < t0; ++t) {                 // warm-up, no writes
        float xx = yb[(size_t)t*NE];
        float yn = (xx - mu)*rsg + bet;
        float d  = __fsub_rn(yn, v);
        v = __fadd_rn(v, __fmul_rn(d, 0.5f));
        v = (v >= 1.0f) ? 0.0f : v;
    }
    float cnt = 0.0f;
    #pragma unroll 4
    for (int t = t0; t < t0 + LCH; ++t) {
        float xx = yb[(size_t)t*NE];
        float yn = (xx - mu)*rsg + bet;
        float d  = __fsub_rn(yn, v);
        v = __fadd_rn(v, __fmul_rn(d, 0.5f));       // v + (x - v)/TAU, TAU=2
        bool sp = (v >= 1.0f);
        if (WS) sb[(size_t)t*NE] = sp ? one : z;
        else    cnt += sp ? 1.0f : 0.0f;
        v = sp ? 0.0f : v;
    }
    if (!WS) pool[(size_t)(b*8 + c)*256 + e] = cnt;
}

// ---- main conv (v2 = best measured): A-frags direct from global (frag-ordered),
//      B via swizzled LDS, 8 phases of 32 c ----
// block: 128e x 256t; wave: 64e x 128t (f=4 e-blocks x g=8 t-blocks of 16x16x32)
__global__ __launch_bounds__(256, 2) void conv_mfma(
    const __hip_bfloat16* __restrict__ Sp,   // [B][TROWS][E] padded spikes
    const __hip_bfloat16* __restrict__ Wfr,  // [k][s][e4][cph][512] frag-ordered, this layer
    const float* __restrict__ bias,
    float* __restrict__ y,                   // [B][T][E]
    float* __restrict__ part)
{
    __shared__ short Bbuf[260*32];           // 260 rows x 32 c (64 B/row, swizzled) = 16640 B
    const int tid  = threadIdx.x;
    const int wave = tid >> 6, lane = tid & 63;
    const int n16  = lane & 15, q = lane >> 4;
    const int we = wave & 1, wt = wave >> 1;
    const int tt = blockIdx.x, et = blockIdx.y, b = blockIdx.z;
    const int t0 = tt * TT;

    f32x4 acc[4][8] = {};
    bf16x8 bfr[8];

    const __hip_bfloat16* Sbase = Sp + ((size_t)b*TROWS + (TPAD - 1 + t0)) * NE;

    for (int ph = 0; ph < 8; ++ph) {
        const int c0 = ph * 32;
        __syncthreads();
        // stage B tile: 258 rows x 32 c, 16B segs swizzled by (row>>1)&3
        for (int idx = tid; idx < 258*4; idx += 256) {
            int r = idx >> 2, sg = idx & 3;
            uint4 d = *(const uint4*)(Sbase + (size_t)r*NE + c0 + sg*8);
            int sgs = sg ^ ((r >> 1) & 3);
            *(uint4*)((char*)Bbuf + r*64 + sgs*16) = d;
        }
        __syncthreads();
        #pragma unroll 1
        for (int kk = 0; kk < 3; ++kk) {
            #pragma unroll
            for (int g = 0; g < 8; ++g) {
                int row = wt*128 + g*16 + n16 + kk;
                int sgs = q ^ ((row >> 1) & 3);
                bfr[g] = *(const bf16x8*)((const char*)Bbuf + row*64 + sgs*16);
            }
            #pragma unroll
            for (int s = 0; s < 2; ++s) {
                const __hip_bfloat16* wb = Wfr
                    + ((((size_t)(kk*2 + s)*16 + (et*8 + we*4))*8 + ph) << 9) + lane*8;
                bf16x8 afr[4];
                #pragma unroll
                for (int f = 0; f < 4; ++f)
                    afr[f] = *(const bf16x8*)(wb + ((size_t)f << 12));
                #pragma unroll
                for (int f = 0; f < 4; ++f)
                    #pragma unroll
                    for (int g = 0; g < 8; ++g)
                        acc[f][g] = __builtin_amdgcn_mfma_f32_16x16x32_bf16(afr[f], bfr[g], acc[f][g], 0, 0, 0);
            }
        }
    }

    // epilogue: C col=n16 (t), row=q*4+reg (e); store y + per-e block stats
    float ls[16], lq[16];
    #pragma unroll
    for (int f = 0; f < 4; ++f) {
        int e_loc = et*128 + we*64 + f*16 + q*4;
        float4 bv = *(const float4*)(bias + e_loc);
        float s0=0,s1=0,s2=0,s3=0, q0=0,q1=0,q2=0,q3=0;
        #pragma unroll
        for (int g = 0; g < 8; ++g) {
            int t = t0 + wt*128 + g*16 + n16;
            f32x4 a = acc[f][g];
            float4 o;
            o.x = a[0] + bv.x; o.y = a[1] + bv.y; o.z = a[2] + bv.z; o.w = a[3] + bv.w;
            *(float4*)(y + ((size_t)b*NT + t)*NE + e_loc) = o;
            s0 += o.x; q0 += o.x*o.x;
            s1 += o.y; q1 += o.y*o.y;
            s2 += o.z; q2 += o.z*o.z;
            s3 += o.w; q3 += o.w*o.w;
        }
        ls[f*4+0]=s0; lq[f*4+0]=q0;
        ls[f*4+1]=s1; lq[f*4+1]=q1;
        ls[f*4+2]=s2; lq[f*4+2]=q2;
        ls[f*4+3]=s3; lq[f*4+3]=q3;
    }
    #pragma unroll
    for (int off = 1; off < 16; off <<= 1) {
        #pragma unroll
        for (int i = 0; i < 16; ++i) {
            ls[i] += __shfl_xor(ls[i], off, 64);
            lq[i] += __shfl_xor(lq[i], off, 64);
        }
    }
    __syncthreads();
    float* red = (float*)Bbuf;                  // reuse LDS: [0..127]=sum, [128..255]=sq
    if (n16 == 0 && wt == 0) {
        #pragma unroll
        for (int f = 0; f < 4; ++f)
            #pragma unroll
            for (int r = 0; r < 4; ++r) {
                int el = we*64 + f*16 + q*4 + r;
                red[el] = ls[f*4+r]; red[128+el] = lq[f*4+r];
            }
    }
    __syncthreads();
    if (n16 == 0 && wt == 1) {
        #pragma unroll
        for (int f = 0; f < 4; ++f)
            #pragma unroll
            for (int r = 0; r < 4; ++r) {
                int el = we*64 + f*16 + q*4 + r;
                red[el] += ls[f*4+r]; red[128+el] += lq[f*4+r];
            }
    }
    __syncthreads();
    if (tid < 128) {
        int p = b*4 + tt;
        part[(size_t)p*512 + et*128 + tid]       = red[tid];
        part[(size_t)p*512 + 256 + et*128 + tid] = red[128 + tid];
    }
}

// ---------------- head final: pooled counts -> [B,E]@[O,E]^T + b ----------------
__global__ void head_final(const float* __restrict__ pool, const float* __restrict__ hw,
                           const float* __restrict__ hb, float* __restrict__ out) {
    int b = blockIdx.x;
    int tid = threadIdx.x;
    __shared__ float pooled[256];
    float s = 0.0f;
    #pragma unroll
    for (int c = 0; c < 8; ++c) s += pool[(size_t)(b*8 + c)*256 + tid];
    pooled[tid] = s * (1.0f/1024.0f);        // exact: integer count / 2^10
    __syncthreads();
    if (tid < NO) {
        float acc = hb[tid];
        for (int c = 0; c < 256; ++c) acc += pooled[c] * hw[tid*256 + c];
        out[b*NO + tid] = acc;
    }
}

// ---------------- launch ----------------
extern "C" void kernel_launch(void* const* d_in, const int* in_sizes, int n_in,
                              void* d_out, int out_size, void* d_ws, size_t ws_size,
                              hipStream_t stream) {
    (void)in_sizes; (void)n_in; (void)out_size; (void)ws_size;
    const float* x       = (const float*)d_in[0];
    const float* conv0_w = (const float*)d_in[1];
    const float* conv0_b = (const float*)d_in[2];
    const float* convs_w = (const float*)d_in[3];
    const float* convs_b = (const float*)d_in[4];
    const float* bn_g    = (const float*)d_in[5];
    const float* bn_b    = (const float*)d_in[6];
    const float* head_w  = (const float*)d_in[7];
    const float* head_b  = (const float*)d_in[8];
    float* out = (float*)d_out;

    char* ws = (char*)d_ws;
    float*          y      = (float*)ws;                              // 67108864 B
    __hip_bfloat16* S      = (__hip_bfloat16*)(ws + 67108864);        // 34603008 B
    __hip_bfloat16* Wfr    = (__hip_bfloat16*)(ws + 101711872);       //  2359296 B
    float*          part   = (float*)(ws + 104071168);                //  1048576 B (512p x 512)
    float4*         lifp   = (float4*)(ws + 105119744);               //     4096 B
    float*          pool   = (float*)(ws + 105123840);                //   524288 B

    conv0_prep<<<1088, 256, 0, stream>>>(x, conv0_w, conv0_b, y, part, convs_w, Wfr);
    stats_final<<<256, 64, 0, stream>>>(part, bn_g, bn_b, lifp, 512);
    lif_kern<true><<<dim3(8, 64), 256, 0, stream>>>(y, lifp, S, nullptr);

    for (int l = 0; l < 3; ++l) {
        conv_mfma<<<dim3(4, 2, 64), 256, 0, stream>>>(S, Wfr + (size_t)l*393216,
                                                      convs_b + l*256, y, part);
        stats_final<<<256, 64, 0, stream>>>(part, bn_g + (l+1)*256, bn_b + (l+1)*256, lifp, 256);
        if (l < 2) lif_kern<true ><<<dim3(8, 64), 256, 0, stream>>>(y, lifp, S, nullptr);
        else       lif_kern<false><<<dim3(8, 64), 256, 0, stream>>>(y, lifp, S, pool);
    }
    head_final<<<64, 256, 0, stream>>>(pool, head_w, head_b, out);
}